// Round 4
// baseline (772.943 us; speedup 1.0000x reference)
//
#include <hip/hip_runtime.h>

// VanillaRNN fused MFMA kernel for MI355X (gfx950).
// B=256, T=512, D=128, H=256, O=128, fp32 in/out.
//
// 16 WGs x 256 threads; each WG owns 16 batch rows for the whole scan.
// Per step: H_new[16,256] = tanh(xW_t + H[16,256] @ W_hh^T) via
// mfma_f32_16x16x32_f16; each of the 4 waves computes a 64-col N-strip.
// W_hh / W_hx B-fragments are VGPR-resident for the entire kernel.
// h is double-buffered in LDS with an XOR swizzle (off ^= (row&7)<<4) so
// A-fragment ds_read_b128s run at the LDS bandwidth floor.
// xW is computed fused per 8-step chunk and kept packed f16 in registers.

typedef _Float16 f16;
typedef _Float16 f16x2 __attribute__((ext_vector_type(2)));
typedef _Float16 f16x4 __attribute__((ext_vector_type(4)));
typedef _Float16 f16x8 __attribute__((ext_vector_type(8)));
typedef float f32x4 __attribute__((ext_vector_type(4)));

#define NB 256
#define NT 512
#define ND 128
#define NH 256
#define NO 128
#define R  16            // batch rows per WG
#define TCH 8            // timesteps per chunk
#define NCH (NT / TCH)   // 64 chunks

__device__ __forceinline__ float fast_tanh(float z) {
  // tanh(z) = 1 - 2/(exp2(z*2*log2e) + 1); exact at +/-inf, no NaN for finite z
  float e = __builtin_amdgcn_exp2f(z * 2.88539008177793f);
  float r = __builtin_amdgcn_rcpf(e + 1.0f);
  return __builtin_fmaf(-2.0f, r, 1.0f);
}

__device__ __forceinline__ f16x8 cvt8(const float* __restrict__ p) {
  f32x4 v0 = *(const f32x4*)p;
  f32x4 v1 = *(const f32x4*)(p + 4);
  f16x8 r;
  r[0] = (f16)v0.x; r[1] = (f16)v0.y; r[2] = (f16)v0.z; r[3] = (f16)v0.w;
  r[4] = (f16)v1.x; r[5] = (f16)v1.y; r[6] = (f16)v1.z; r[7] = (f16)v1.w;
  return r;
}

__global__ __launch_bounds__(256, 1)
void rnn_mfma(const float* __restrict__ x,
              const float* __restrict__ Wx, const float* __restrict__ bx,
              const float* __restrict__ Wh, const float* __restrict__ bh,
              const float* __restrict__ Wp, const float* __restrict__ bp,
              float* __restrict__ out)
{
  const int wg  = blockIdx.x;    // 0..15
  const int tid = threadIdx.x;
  const int w   = tid >> 6;      // wave 0..3 (owns cols [w*64, w*64+64))
  const int l   = tid & 63;
  const int l15 = l & 15;
  const int g   = l >> 4;        // 0..3 (K-subblock / C row group)

  __shared__ alignas(16) f16 xlds[TCH * R][ND];   // 32 KB, swizzled A-layout
  __shared__ alignas(16) f16 hbuf[2][R][NH];      // 16 KB, swizzled, dbuf

  // ---- W_hh B-fragments (N-strip of 64 cols), VGPR-resident ----
  f16x8 fWh[4][8];   // [coltile][ktile], 128 VGPRs
  #pragma unroll
  for (int ct = 0; ct < 4; ++ct) {
    const int j = w * 64 + ct * 16 + l15;
    #pragma unroll
    for (int kt = 0; kt < 8; ++kt)
      fWh[ct][kt] = cvt8(Wh + (size_t)j * NH + kt * 32 + g * 8);
  }
  // ---- W_hx B-fragments ----
  f16x8 fWx[4][4];   // 64 VGPRs
  #pragma unroll
  for (int ct = 0; ct < 4; ++ct) {
    const int j = w * 64 + ct * 16 + l15;
    #pragma unroll
    for (int kt = 0; kt < 4; ++kt)
      fWx[ct][kt] = cvt8(Wx + (size_t)j * ND + kt * 32 + g * 8);
  }
  float bias[4];
  #pragma unroll
  for (int ct = 0; ct < 4; ++ct) {
    const int j = w * 64 + ct * 16 + l15;
    bias[ct] = bx[j] + bh[j];
  }

  // ---- h0 = 0 ----
  {
    unsigned* hz = (unsigned*)&hbuf[0][0][0];
    #pragma unroll
    for (int k = 0; k < (R * NH / 2) / 256; ++k) hz[tid + k * 256] = 0u;
  }
  __syncthreads();

  int cur = 0;
  f16x2 xwb[TCH][4][2];   // packed xW+bias for the chunk, 64 VGPRs

  const int srow = tid >> 4;   // staging: 16 threads per batch row
  const int sq   = tid & 15;
  const float* xrow = x + (size_t)(wg * R + srow) * NT * ND;

  #pragma unroll 1
  for (int c = 0; c < NCH; ++c) {
    // ---- stage x[rows, 8t, 128d] -> LDS f16, swizzled A-layout ----
    const float* xc = xrow + (size_t)c * TCH * ND;
    #pragma unroll
    for (int jj = 0; jj < 16; ++jj) {
      const int f = (sq + jj * 16) * 4;   // float idx in 1024-float row chunk
      f32x4 v = *(const f32x4*)(xc + f);
      const int t = f >> 7;               // /ND
      const int d = f & (ND - 1);
      const int m = t * R + srow;         // M index (t-major tiles of 16 rows)
      f16x4 h4;
      h4[0] = (f16)v.x; h4[1] = (f16)v.y; h4[2] = (f16)v.z; h4[3] = (f16)v.w;
      *(f16x4*)((char*)&xlds[m][0] + ((2 * d) ^ ((m & 7) << 4))) = h4;
    }
    __syncthreads();

    // ---- xW for the chunk via MFMA; keep (xW + bias) packed in regs ----
    #pragma unroll
    for (int t = 0; t < TCH; ++t) {
      f16x8 a[4];
      #pragma unroll
      for (int kt = 0; kt < 4; ++kt) {
        const int m = t * R + l15;
        a[kt] = *(const f16x8*)((char*)&xlds[m][0] +
                 ((kt * 64 + g * 16) ^ ((m & 7) << 4)));
      }
      #pragma unroll
      for (int ct = 0; ct < 4; ++ct) {
        f32x4 ac = {bias[ct], bias[ct], bias[ct], bias[ct]};
        #pragma unroll
        for (int kt = 0; kt < 4; ++kt)
          ac = __builtin_amdgcn_mfma_f32_16x16x32_f16(a[kt], fWx[ct][kt], ac, 0, 0, 0);
        f16x2 p0; p0[0] = (f16)ac[0]; p0[1] = (f16)ac[1];
        f16x2 p1; p1[0] = (f16)ac[2]; p1[1] = (f16)ac[3];
        xwb[t][ct][0] = p0;
        xwb[t][ct][1] = p1;
      }
    }
    // (no barrier: the step-loop barriers order xlds reuse for next chunk)

    // ---- TCH serial recurrence steps ----
    #pragma unroll
    for (int s = 0; s < TCH; ++s) {
      f16x8 a[8];
      #pragma unroll
      for (int kt = 0; kt < 8; ++kt) {
        const int m = l15;
        a[kt] = *(const f16x8*)((char*)&hbuf[cur][m][0] +
                 ((kt * 64 + g * 16) ^ ((m & 7) << 4)));
      }
      const int nxt = cur ^ 1;
      #pragma unroll
      for (int ct = 0; ct < 4; ++ct) {
        f32x4 ac  = {(float)xwb[s][ct][0][0], (float)xwb[s][ct][0][1],
                     (float)xwb[s][ct][1][0], (float)xwb[s][ct][1][1]};
        f32x4 ac2 = {0.f, 0.f, 0.f, 0.f};
        #pragma unroll
        for (int kt = 0; kt < 4; ++kt) {   // two interleaved chains halve dep latency
          ac  = __builtin_amdgcn_mfma_f32_16x16x32_f16(a[2*kt],     fWh[ct][2*kt],     ac,  0, 0, 0);
          ac2 = __builtin_amdgcn_mfma_f32_16x16x32_f16(a[2*kt + 1], fWh[ct][2*kt + 1], ac2, 0, 0, 0);
        }
        #pragma unroll
        for (int rg = 0; rg < 4; ++rg) {
          const float th = fast_tanh(ac[rg] + ac2[rg]);
          const int row = g * 4 + rg;              // C layout: row=(l>>4)*4+reg
          const int col = w * 64 + ct * 16 + l15;  //           col=lane&15
          *(f16*)((char*)&hbuf[nxt][row][0] +
                  ((2 * col) ^ ((row & 7) << 4))) = (f16)th;
        }
      }
      cur = nxt;
      __syncthreads();
    }
  }

  // ---- output projection: out[b,:] = h_T @ W_ph^T + b_ph ----
  f16x8 ah[8];
  #pragma unroll
  for (int kt = 0; kt < 8; ++kt) {
    const int m = l15;
    ah[kt] = *(const f16x8*)((char*)&hbuf[cur][m][0] +
             ((kt * 64 + g * 16) ^ ((m & 7) << 4)));
  }
  #pragma unroll
  for (int ct = 0; ct < 2; ++ct) {           // O=128 -> 32 cols per wave
    const int o = w * 32 + ct * 16 + l15;
    f32x4 ac = {bp[o], bp[o], bp[o], bp[o]};
    #pragma unroll
    for (int kt = 0; kt < 8; ++kt) {
      f16x8 bfr = cvt8(Wp + (size_t)o * NH + kt * 32 + g * 8);
      ac = __builtin_amdgcn_mfma_f32_16x16x32_f16(ah[kt], bfr, ac, 0, 0, 0);
    }
    #pragma unroll
    for (int rg = 0; rg < 4; ++rg) {
      const int row = g * 4 + rg;
      out[(size_t)(wg * R + row) * NO + o] = ac[rg];
    }
  }
}

extern "C" void kernel_launch(void* const* d_in, const int* in_sizes, int n_in,
                              void* d_out, int out_size, void* d_ws, size_t ws_size,
                              hipStream_t stream) {
  const float* x   = (const float*)d_in[0];
  const float* whx = (const float*)d_in[1];
  const float* bhx = (const float*)d_in[2];
  const float* whh = (const float*)d_in[3];
  const float* bhh = (const float*)d_in[4];
  const float* wph = (const float*)d_in[5];
  const float* bph = (const float*)d_in[6];
  float* out = (float*)d_out;

  rnn_mfma<<<dim3(NB / R), dim3(256), 0, stream>>>(x, whx, bhx, whh, bhh, wph, bph, out);
}